// Round 2
// baseline (378.269 us; speedup 1.0000x reference)
//
#include <hip/hip_runtime.h>
#include <hip/hip_bf16.h>

#define IN_FT  128
#define OUT_FT 32
#define GEMM_ROWS 64
#define PITCH  132
#define SCAN_BLOCKS 250

// -------------------- support = seq @ weight --------------------
__global__ __launch_bounds__(256) void gcn_gemm(const float* __restrict__ seq,
                                                const float* __restrict__ w,
                                                float* __restrict__ sup,
                                                int n) {
    __shared__ __align__(16) float lw[IN_FT * OUT_FT];
    __shared__ __align__(16) float ls[GEMM_ROWS * PITCH];

    const int tid = threadIdx.x;
    for (int i = tid; i < (IN_FT * OUT_FT) / 4; i += 256)
        ((float4*)lw)[i] = ((const float4*)w)[i];

    const int base = blockIdx.x * GEMM_ROWS;
    for (int i = tid; i < GEMM_ROWS * (IN_FT / 4); i += 256) {
        int r  = i >> 5;
        int kc = i & 31;
        int row = base + r;
        float4 v = make_float4(0.f, 0.f, 0.f, 0.f);
        if (row < n)
            v = ((const float4*)(seq + (size_t)row * IN_FT))[kc];
        *(float4*)&ls[r * PITCH + kc * 4] = v;
    }
    __syncthreads();

    const int cg = (tid & 7) * 4;
    const int rp = tid >> 3;
    const int r0 = rp * 2, r1 = r0 + 1;

    float4 acc0 = make_float4(0.f, 0.f, 0.f, 0.f);
    float4 acc1 = make_float4(0.f, 0.f, 0.f, 0.f);

#define FMA4(acc, s, wv) \
    acc.x = fmaf((s), (wv).x, acc.x); \
    acc.y = fmaf((s), (wv).y, acc.y); \
    acc.z = fmaf((s), (wv).z, acc.z); \
    acc.w = fmaf((s), (wv).w, acc.w);

    for (int k = 0; k < IN_FT; k += 4) {
        float4 s0 = *(const float4*)&ls[r0 * PITCH + k];
        float4 s1 = *(const float4*)&ls[r1 * PITCH + k];
        float4 w0 = *(const float4*)&lw[(k + 0) * OUT_FT + cg];
        float4 w1 = *(const float4*)&lw[(k + 1) * OUT_FT + cg];
        float4 w2 = *(const float4*)&lw[(k + 2) * OUT_FT + cg];
        float4 w3 = *(const float4*)&lw[(k + 3) * OUT_FT + cg];
        FMA4(acc0, s0.x, w0); FMA4(acc0, s0.y, w1);
        FMA4(acc0, s0.z, w2); FMA4(acc0, s0.w, w3);
        FMA4(acc1, s1.x, w0); FMA4(acc1, s1.y, w1);
        FMA4(acc1, s1.z, w2); FMA4(acc1, s1.w, w3);
    }
#undef FMA4

    int row0 = base + r0;
    if (row0 < n) *(float4*)&sup[(size_t)row0 * OUT_FT + cg] = acc0;
    int row1 = base + r1;
    if (row1 < n) *(float4*)&sup[(size_t)row1 * OUT_FT + cg] = acc1;
}

// -------------------- CSR build: histogram --------------------
__global__ __launch_bounds__(256) void gcn_hist(const int* __restrict__ erow,
                                                int* __restrict__ cnt, int ne) {
    int e = blockIdx.x * 256 + threadIdx.x;
    if (e < ne) atomicAdd(&cnt[erow[e]], 1);
}

// -------------------- scan pass 1: per-chunk reduce --------------------
__global__ __launch_bounds__(256) void gcn_reduce(const int* __restrict__ cnt,
                                                  int* __restrict__ bsum,
                                                  int n, int chunk) {
    int b = blockIdx.x, t = threadIdx.x;
    int beg = b * chunk;
    int end = min(beg + chunk, n);
    int s = 0;
    for (int i = beg + t; i < end; i += 256) s += cnt[i];
    for (int off = 32; off; off >>= 1) s += __shfl_down(s, off, 64);
    __shared__ int ls[4];
    if ((t & 63) == 0) ls[t >> 6] = s;
    __syncthreads();
    if (t == 0) bsum[b] = ls[0] + ls[1] + ls[2] + ls[3];
}

// -------------------- scan pass 2: scan chunk sums (1 block) --------------------
__global__ __launch_bounds__(256) void gcn_scan_bsum(int* __restrict__ bsum, int nb) {
    __shared__ int s[256];
    int t = threadIdx.x;
    int v = (t < nb) ? bsum[t] : 0;
    s[t] = v;
    __syncthreads();
    for (int off = 1; off < 256; off <<= 1) {
        int x = (t >= off) ? s[t - off] : 0;
        __syncthreads();
        s[t] += x;
        __syncthreads();
    }
    if (t < nb) bsum[t] = s[t] - v;   // exclusive
}

// -------------------- scan pass 3: per-chunk exclusive scan --------------------
__global__ __launch_bounds__(256) void gcn_scan(const int* __restrict__ cnt,
                                                const int* __restrict__ bsum,
                                                int* __restrict__ start,
                                                int* __restrict__ cursor,
                                                int n, int chunk) {
    __shared__ int s[256];
    int b = blockIdx.x, t = threadIdx.x;
    int beg = b * chunk;
    int carry = bsum[b];
    int ntile = (chunk + 255) / 256;
    for (int tile = 0; tile < ntile; ++tile) {
        int loc = tile * 256 + t;
        int idx = beg + loc;
        int v = (idx < n && loc < chunk) ? cnt[idx] : 0;
        s[t] = v;
        __syncthreads();
        for (int off = 1; off < 256; off <<= 1) {
            int x = (t >= off) ? s[t - off] : 0;
            __syncthreads();
            s[t] += x;
            __syncthreads();
        }
        int ex = s[t] - v;
        if (idx < n && loc < chunk) {
            start[idx]  = carry + ex;
            cursor[idx] = carry + ex;
        }
        int tot = s[255];
        __syncthreads();
        carry += tot;
    }
}

// -------------------- reorder edges into CSR order --------------------
__global__ __launch_bounds__(256) void gcn_reorder(const int* __restrict__ erow,
                                                   const int* __restrict__ ecol,
                                                   const float* __restrict__ eval,
                                                   int* __restrict__ cursor,
                                                   int* __restrict__ csr_col,
                                                   float* __restrict__ csr_val,
                                                   int ne) {
    int e = blockIdx.x * 256 + threadIdx.x;
    if (e >= ne) return;
    int r = erow[e];
    int p = atomicAdd(&cursor[r], 1);
    csr_col[p] = ecol[e];
    csr_val[p] = eval[e];
}

// -------------------- gather: one wave per row, relu fused --------------------
__global__ __launch_bounds__(256) void gcn_gather(const int* __restrict__ start,
                                                  const int* __restrict__ cnt,
                                                  const int* __restrict__ csr_col,
                                                  const float* __restrict__ csr_val,
                                                  const float* __restrict__ sup,
                                                  float* __restrict__ out, int n) {
    int wave = (blockIdx.x * 256 + threadIdx.x) >> 6;
    int lane = threadIdx.x & 63;
    if (wave >= n) return;
    int base = start[wave];
    int c    = cnt[wave];
    int col  = lane & 31;
    int half = lane >> 5;
    float acc = 0.f;
    for (int j = half; j < c; j += 2) {
        int   cj = csr_col[base + j];
        float vj = csr_val[base + j];
        acc = fmaf(vj, sup[(size_t)cj * OUT_FT + col], acc);
    }
    acc += __shfl_down(acc, 32, 64);
    if (half == 0) out[(size_t)wave * OUT_FT + col] = fmaxf(acc, 0.f);
}

// -------------------- fallback path (round-1) --------------------
__global__ __launch_bounds__(256) void gcn_scatter(const int* __restrict__ erow,
                                                   const int* __restrict__ ecol,
                                                   const float* __restrict__ eval,
                                                   const float* __restrict__ sup,
                                                   float* __restrict__ out,
                                                   int n_edges) {
    long long g = (long long)blockIdx.x * 256 + threadIdx.x;
    int e = (int)(g >> 5);
    int c = (int)(g & 31);
    if (e >= n_edges) return;
    int r  = erow[e];
    int cl = ecol[e];
    float v = eval[e];
    atomicAdd(out + (size_t)r * OUT_FT + c, v * sup[(size_t)cl * OUT_FT + c]);
}

__global__ __launch_bounds__(256) void gcn_relu(float4* __restrict__ out, int n4) {
    int i = blockIdx.x * 256 + threadIdx.x;
    if (i < n4) {
        float4 v = out[i];
        v.x = fmaxf(v.x, 0.f); v.y = fmaxf(v.y, 0.f);
        v.z = fmaxf(v.z, 0.f); v.w = fmaxf(v.w, 0.f);
        out[i] = v;
    }
}

extern "C" void kernel_launch(void* const* d_in, const int* in_sizes, int n_in,
                              void* d_out, int out_size, void* d_ws, size_t ws_size,
                              hipStream_t stream) {
    const float* seq  = (const float*)d_in[0];
    const float* w    = (const float*)d_in[1];
    const int*   erow = (const int*)d_in[2];
    const int*   ecol = (const int*)d_in[3];
    const float* eval = (const float*)d_in[4];
    float* out = (float*)d_out;

    const int n_nodes = in_sizes[0] / IN_FT;
    const int n_edges = in_sizes[2];

    // ---- workspace layout ----
    char* ws = (char*)d_ws;
    size_t off = 0;
    auto alloc = [&](size_t bytes) {
        char* p = ws + off;
        off += (bytes + 255) & ~(size_t)255;
        return p;
    };
    float* sup     = (float*)alloc((size_t)n_nodes * OUT_FT * sizeof(float));
    int*   cnt     = (int*)  alloc((size_t)n_nodes * sizeof(int));
    int*   start   = (int*)  alloc((size_t)n_nodes * sizeof(int));
    int*   cursor  = (int*)  alloc((size_t)n_nodes * sizeof(int));
    int*   bsum    = (int*)  alloc(SCAN_BLOCKS * sizeof(int));
    int*   csr_col = (int*)  alloc((size_t)n_edges * sizeof(int));
    float* csr_val = (float*)alloc((size_t)n_edges * sizeof(float));
    bool have_ws = (off <= ws_size);

    // 1) support = seq @ weight
    int gemm_blocks = (n_nodes + GEMM_ROWS - 1) / GEMM_ROWS;
    gcn_gemm<<<gemm_blocks, 256, 0, stream>>>(seq, w, sup, n_nodes);

    if (have_ws) {
        // 2) CSR build
        hipMemsetAsync(cnt, 0, (size_t)n_nodes * sizeof(int), stream);
        gcn_hist<<<(n_edges + 255) / 256, 256, 0, stream>>>(erow, cnt, n_edges);
        int chunk = (n_nodes + SCAN_BLOCKS - 1) / SCAN_BLOCKS;
        gcn_reduce<<<SCAN_BLOCKS, 256, 0, stream>>>(cnt, bsum, n_nodes, chunk);
        gcn_scan_bsum<<<1, 256, 0, stream>>>(bsum, SCAN_BLOCKS);
        gcn_scan<<<SCAN_BLOCKS, 256, 0, stream>>>(cnt, bsum, start, cursor,
                                                  n_nodes, chunk);
        gcn_reorder<<<(n_edges + 255) / 256, 256, 0, stream>>>(
            erow, ecol, eval, cursor, csr_col, csr_val, n_edges);
        // 3) gather + relu (writes every output element; no memset needed)
        gcn_gather<<<(n_nodes + 3) / 4, 256, 0, stream>>>(
            start, cnt, csr_col, csr_val, sup, out, n_nodes);
    } else {
        // fallback: atomic scatter
        hipMemsetAsync(d_out, 0, (size_t)out_size * sizeof(float), stream);
        long long work = (long long)n_edges * OUT_FT;
        gcn_scatter<<<(int)((work + 255) / 256), 256, 0, stream>>>(
            erow, ecol, eval, sup, out, n_edges);
        int n4 = out_size / 4;
        gcn_relu<<<(n4 + 255) / 256, 256, 0, stream>>>((float4*)out, n4);
    }
}